// Round 1
// baseline (1413.312 us; speedup 1.0000x reference)
//
#include <hip/hip_runtime.h>

#define N_NODES 50000
#define N_EDGES 1600000
#define IN_F 128
#define OUT_F 32
#define HEADS 4
#define NEG_SLOPE 0.2f

// ---- monotone float<->uint encoding for atomicMax on signed floats ----
__device__ __forceinline__ unsigned enc_f(float f) {
    unsigned u = __float_as_uint(f);
    return (u & 0x80000000u) ? ~u : (u | 0x80000000u);
}
__device__ __forceinline__ float dec_f(unsigned u) {
    return (u & 0x80000000u) ? __uint_as_float(u & 0x7fffffffu)
                             : __uint_as_float(~u);
}

// K1: per-head projection h[h][n][o] = sum_i x[n][i]*W[h][i][o]
//     plus attn_src[h][n] = h . a_src[h], attn_dst[h][n] = h . a_dst[h]
__global__ __launch_bounds__(128) void k_project(
    const float* __restrict__ x, const float* __restrict__ W,
    const float* __restrict__ a_src, const float* __restrict__ a_dst,
    float* __restrict__ h_buf, float* __restrict__ attn_s,
    float* __restrict__ attn_d)
{
    __shared__ float xs[IN_F];
    const int n = blockIdx.x;
    const int tid = threadIdx.x;
    xs[tid] = x[n * IN_F + tid];
    __syncthreads();
    const int head = tid >> 5;      // 4 heads x 32 outs = 128 threads
    const int o = tid & 31;
    const float* Wp = W + head * IN_F * OUT_F + o;
    float acc = 0.f;
    #pragma unroll 8
    for (int k = 0; k < IN_F; ++k) acc += xs[k] * Wp[k * OUT_F];
    h_buf[(head * N_NODES + n) * OUT_F + o] = acc;

    float ts = acc * a_src[head * OUT_F + o];
    float td = acc * a_dst[head * OUT_F + o];
    #pragma unroll
    for (int m = 16; m >= 1; m >>= 1) {
        ts += __shfl_xor(ts, m, 32);
        td += __shfl_xor(td, m, 32);
    }
    if (o == 0) {
        attn_s[head * N_NODES + n] = ts;
        attn_d[head * N_NODES + n] = td;
    }
}

// K2: per-edge logits (leaky-relu * weight), global max via encoded atomicMax
__global__ __launch_bounds__(256) void k_edge(
    const int* __restrict__ ei, const float* __restrict__ ew,
    const float* __restrict__ attn_s, const float* __restrict__ attn_d,
    float* __restrict__ e_buf, unsigned* __restrict__ maxenc)
{
    const int e = blockIdx.x * 256 + threadIdx.x;
    float lm = -1e30f;
    if (e < N_EDGES) {
        const int src = ei[e];
        const int dst = ei[N_EDGES + e];
        const float w = ew[e];
        #pragma unroll
        for (int h = 0; h < HEADS; ++h) {
            float v = attn_s[h * N_NODES + src] + attn_d[h * N_NODES + dst];
            v = (v >= 0.f) ? v : NEG_SLOPE * v;
            v *= w;
            e_buf[h * N_EDGES + e] = v;
            lm = fmaxf(lm, v);
        }
    }
    #pragma unroll
    for (int m = 32; m >= 1; m >>= 1) lm = fmaxf(lm, __shfl_xor(lm, m));
    if ((threadIdx.x & 63) == 0) atomicMax(maxenc, enc_f(lm));
}

// K3: e_exp = exp(e - max), accumulate segment denominators per (head,dst)
__global__ __launch_bounds__(256) void k_exp(
    const int* __restrict__ ei, float* __restrict__ e_buf,
    const unsigned* __restrict__ maxenc, float* __restrict__ denom)
{
    const int e = blockIdx.x * 256 + threadIdx.x;
    if (e >= N_EDGES) return;
    const float mx = dec_f(*maxenc);
    const int dst = ei[N_EDGES + e];
    #pragma unroll
    for (int h = 0; h < HEADS; ++h) {
        float v = __expf(e_buf[h * N_EDGES + e] - mx);
        e_buf[h * N_EDGES + e] = v;
        atomicAdd(&denom[h * N_NODES + dst], v);
    }
}

// K4: per-edge message scatter: out[dst][h*32+o] += h[h][src][o] * alpha
//     2 edges per 256-thread block; 128 threads (=H*O columns) per edge.
__global__ __launch_bounds__(256) void k_scatter(
    const int* __restrict__ ei, const float* __restrict__ e_buf,
    const float* __restrict__ denom, const float* __restrict__ h_buf,
    float* __restrict__ out)
{
    const int e = blockIdx.x * 2 + (threadIdx.x >> 7);
    if (e >= N_EDGES) return;
    const int col = threadIdx.x & 127;
    const int head = col >> 5;
    const int o = col & 31;
    const int src = ei[e];
    const int dst = ei[N_EDGES + e];
    const float ex = e_buf[head * N_EDGES + e];
    const float den = denom[head * N_NODES + dst];
    const float alpha = ex / (den + 1e-10f);
    const float val = h_buf[(head * N_NODES + src) * OUT_F + o] * alpha;
    atomicAdd(&out[dst * (HEADS * OUT_F) + col], val);
}

extern "C" void kernel_launch(void* const* d_in, const int* in_sizes, int n_in,
                              void* d_out, int out_size, void* d_ws, size_t ws_size,
                              hipStream_t stream) {
    const float* x   = (const float*)d_in[0];
    const int*   ei  = (const int*)d_in[1];
    const float* ew  = (const float*)d_in[2];
    const float* W   = (const float*)d_in[3];
    const float* a_s = (const float*)d_in[4];
    const float* a_d = (const float*)d_in[5];
    float* out = (float*)d_out;

    float* ws      = (float*)d_ws;
    float* h_buf   = ws;                                  // H*N*O   = 6.4M floats
    float* e_buf   = h_buf + (size_t)HEADS * N_NODES * OUT_F; // H*E = 6.4M floats
    float* attn_s  = e_buf + (size_t)HEADS * N_EDGES;     // H*N = 200K
    float* attn_d  = attn_s + HEADS * N_NODES;            // H*N = 200K
    float* denom   = attn_d + HEADS * N_NODES;            // H*N = 200K
    unsigned* maxenc = (unsigned*)(denom + HEADS * N_NODES);

    // zero denom + maxenc (contiguous) and the output accumulator
    hipMemsetAsync(denom, 0, (size_t)(HEADS * N_NODES + 1) * sizeof(float), stream);
    hipMemsetAsync(d_out, 0, (size_t)out_size * sizeof(float), stream);

    k_project<<<N_NODES, 128, 0, stream>>>(x, W, a_s, a_d, h_buf, attn_s, attn_d);
    k_edge   <<<N_EDGES / 256, 256, 0, stream>>>(ei, ew, attn_s, attn_d, e_buf, maxenc);
    k_exp    <<<N_EDGES / 256, 256, 0, stream>>>(ei, e_buf, maxenc, denom);
    k_scatter<<<N_EDGES / 2, 256, 0, stream>>>(ei, e_buf, denom, h_buf, out);
}

// Round 2
// 610.518 us; speedup vs baseline: 2.3149x; 2.3149x over previous
//
#include <hip/hip_runtime.h>

#define N_NODES 50000
#define N_EDGES 1600000
#define IN_F 128
#define OUT_F 32
#define HEADS 4
#define NEG_SLOPE 0.2f
#define HO (HEADS * OUT_F)

// K1: per-head projection h[h][n][o] = sum_i x[n][i]*W[h][i][o]
//     plus attn_src[h][n] = h . a_src[h], attn_dst[h][n] = h . a_dst[h]
__global__ __launch_bounds__(128) void k_project(
    const float* __restrict__ x, const float* __restrict__ W,
    const float* __restrict__ a_src, const float* __restrict__ a_dst,
    float* __restrict__ h_buf, float* __restrict__ attn_s,
    float* __restrict__ attn_d)
{
    __shared__ float xs[IN_F];
    const int n = blockIdx.x;
    const int tid = threadIdx.x;
    xs[tid] = x[n * IN_F + tid];
    __syncthreads();
    const int head = tid >> 5;      // 4 heads x 32 outs = 128 threads
    const int o = tid & 31;
    const float* Wp = W + head * IN_F * OUT_F + o;
    float acc = 0.f;
    #pragma unroll 8
    for (int k = 0; k < IN_F; ++k) acc += xs[k] * Wp[k * OUT_F];
    h_buf[(head * N_NODES + n) * OUT_F + o] = acc;

    float ts = acc * a_src[head * OUT_F + o];
    float td = acc * a_dst[head * OUT_F + o];
    #pragma unroll
    for (int m = 16; m >= 1; m >>= 1) {
        ts += __shfl_xor(ts, m, 32);
        td += __shfl_xor(td, m, 32);
    }
    if (o == 0) {
        attn_s[head * N_NODES + n] = ts;
        attn_d[head * N_NODES + n] = td;
    }
}

// K2: histogram of in-degrees
__global__ __launch_bounds__(256) void k_hist(
    const int* __restrict__ ei, int* __restrict__ counts)
{
    const int e = blockIdx.x * 256 + threadIdx.x;
    if (e < N_EDGES) atomicAdd(&counts[ei[N_EDGES + e]], 1);
}

// K3: exclusive scan of counts -> offsets[N+1]; cursor initialized to offsets
__global__ __launch_bounds__(1024) void k_scan(
    const int* __restrict__ counts, int* __restrict__ offsets,
    int* __restrict__ cursor)
{
    __shared__ int part[1024];
    const int t = threadIdx.x;
    const int CH = (N_NODES + 1023) / 1024;   // 49
    const int lo = t * CH;
    const int hi = min(lo + CH, N_NODES);
    int s = 0;
    for (int i = lo; i < hi; ++i) s += counts[i];
    part[t] = s;
    __syncthreads();
    // Hillis-Steele inclusive scan over 1024 partials
    for (int d = 1; d < 1024; d <<= 1) {
        int v = (t >= d) ? part[t - d] : 0;
        __syncthreads();
        part[t] += v;
        __syncthreads();
    }
    int base = (t == 0) ? 0 : part[t - 1];
    for (int i = lo; i < hi; ++i) {
        offsets[i] = base;
        cursor[i]  = base;
        base += counts[i];
    }
    if (t == 1023) offsets[N_NODES] = base;   // == N_EDGES
}

// K4: scatter edges into dst-sorted order: sorted[pos] = (src, edge_id)
__global__ __launch_bounds__(256) void k_reorder(
    const int* __restrict__ ei, int* __restrict__ cursor,
    int2* __restrict__ sorted)
{
    const int e = blockIdx.x * 256 + threadIdx.x;
    if (e >= N_EDGES) return;
    const int src = ei[e];
    const int dst = ei[N_EDGES + e];
    const int pos = atomicAdd(&cursor[dst], 1);
    sorted[pos] = make_int2(src, e);
}

// K5: per-dst gather-aggregate with online per-(dst,head) softmax.
//     One 128-thread block per dst node; thread = (head, out-col).
//     No atomics; out written exactly once, fully coalesced.
__global__ __launch_bounds__(128) void k_aggregate(
    const int2* __restrict__ sorted, const int* __restrict__ offsets,
    const float* __restrict__ ew, const float* __restrict__ attn_s,
    const float* __restrict__ attn_d, const float* __restrict__ h_buf,
    float* __restrict__ out)
{
    const int dst = blockIdx.x;
    const int tid = threadIdx.x;
    const int head = tid >> 5;
    const int o = tid & 31;
    const int beg = offsets[dst];
    const int end = offsets[dst + 1];
    const float ad = attn_d[head * N_NODES + dst];

    float m = -1e30f, den = 0.f, acc = 0.f;
    for (int p = beg; p < end; ++p) {
        const int2 se = sorted[p];               // (src, eid)
        const float w = ew[se.y];
        float v = attn_s[head * N_NODES + se.x] + ad;
        v = (v >= 0.f) ? v : NEG_SLOPE * v;
        v *= w;
        const float mn = fmaxf(m, v);
        const float scale = __expf(m - mn);      // 0 on first iteration
        const float pe = __expf(v - mn);
        const float hv = h_buf[(head * N_NODES + se.x) * OUT_F + o];
        den = den * scale + pe;
        acc = acc * scale + pe * hv;
        m = mn;
    }
    out[dst * HO + tid] = acc / (den + 1e-10f);
}

extern "C" void kernel_launch(void* const* d_in, const int* in_sizes, int n_in,
                              void* d_out, int out_size, void* d_ws, size_t ws_size,
                              hipStream_t stream) {
    const float* x   = (const float*)d_in[0];
    const int*   ei  = (const int*)d_in[1];
    const float* ew  = (const float*)d_in[2];
    const float* W   = (const float*)d_in[3];
    const float* a_s = (const float*)d_in[4];
    const float* a_d = (const float*)d_in[5];
    float* out = (float*)d_out;

    float* ws     = (float*)d_ws;
    float* h_buf  = ws;                                        // 6.4M floats
    float* attn_s = h_buf + (size_t)HEADS * N_NODES * OUT_F;   // 200K
    float* attn_d = attn_s + HEADS * N_NODES;                  // 200K
    int2*  sorted = (int2*)(attn_d + HEADS * N_NODES);         // 1.6M int2 (8B-aligned)
    int*   counts = (int*)(sorted + N_EDGES);                  // 50K
    int*   offsets= counts + N_NODES;                          // 50K+1
    int*   cursor = offsets + N_NODES + 1;                     // 50K

    hipMemsetAsync(counts, 0, N_NODES * sizeof(int), stream);

    k_project  <<<N_NODES, 128, 0, stream>>>(x, W, a_s, a_d, h_buf, attn_s, attn_d);
    k_hist     <<<(N_EDGES + 255) / 256, 256, 0, stream>>>(ei, counts);
    k_scan     <<<1, 1024, 0, stream>>>(counts, offsets, cursor);
    k_reorder  <<<(N_EDGES + 255) / 256, 256, 0, stream>>>(ei, cursor, sorted);
    k_aggregate<<<N_NODES, 128, 0, stream>>>(sorted, offsets, ew, attn_s, attn_d,
                                             h_buf, out);
}

// Round 3
// 568.052 us; speedup vs baseline: 2.4880x; 1.0748x over previous
//
#include <hip/hip_runtime.h>
#include <hip/hip_bf16.h>

#define N_NODES 50000
#define N_EDGES 1600000
#define IN_F 128
#define OUT_F 32
#define HEADS 4
#define NEG_SLOPE 0.2f
#define HO (HEADS * OUT_F)

// F1: blocks [0, N_NODES) do per-node projection; blocks beyond do the
// in-degree histogram (memory/atomic-bound, hides under VALU-bound project).
__global__ __launch_bounds__(128) void k_fused1(
    const float* __restrict__ x, const float* __restrict__ W,
    const float* __restrict__ a_src, const float* __restrict__ a_dst,
    const int* __restrict__ ei,
    __hip_bfloat16* __restrict__ h_bf, float* __restrict__ attn_s4,
    float* __restrict__ attn_d4, int* __restrict__ counts)
{
    const int b = blockIdx.x;
    const int tid = threadIdx.x;
    if (b >= N_NODES) {                       // histogram part
        const int e = (b - N_NODES) * 128 + tid;
        if (e < N_EDGES) atomicAdd(&counts[ei[N_EDGES + e]], 1);
        return;
    }
    __shared__ float xs[IN_F];
    xs[tid] = x[b * IN_F + tid];
    __syncthreads();
    const int head = tid >> 5;                // 4 heads x 32 outs
    const int o = tid & 31;
    const float* Wp = W + head * IN_F * OUT_F + o;
    float acc = 0.f;
    #pragma unroll 8
    for (int k = 0; k < IN_F; ++k) acc += xs[k] * Wp[k * OUT_F];
    h_bf[b * HO + tid] = __float2bfloat16(acc);   // [N][H*32] bf16

    float ts = acc * a_src[head * OUT_F + o];
    float td = acc * a_dst[head * OUT_F + o];
    #pragma unroll
    for (int m = 16; m >= 1; m >>= 1) {
        ts += __shfl_xor(ts, m, 32);
        td += __shfl_xor(td, m, 32);
    }
    if (o == 0) {                              // [N][4] interleaved
        attn_s4[b * HEADS + head] = ts;
        attn_d4[b * HEADS + head] = td;
    }
}

// K3: exclusive scan of counts -> offsets[N+1]; cursor initialized to offsets
__global__ __launch_bounds__(1024) void k_scan(
    const int* __restrict__ counts, int* __restrict__ offsets,
    int* __restrict__ cursor)
{
    __shared__ int part[1024];
    const int t = threadIdx.x;
    const int CH = (N_NODES + 1023) / 1024;   // 49
    const int lo = t * CH;
    const int hi = min(lo + CH, N_NODES);
    int s = 0;
    for (int i = lo; i < hi; ++i) s += counts[i];
    part[t] = s;
    __syncthreads();
    for (int d = 1; d < 1024; d <<= 1) {
        int v = (t >= d) ? part[t - d] : 0;
        __syncthreads();
        part[t] += v;
        __syncthreads();
    }
    int base = (t == 0) ? 0 : part[t - 1];
    for (int i = lo; i < hi; ++i) {
        offsets[i] = base;
        cursor[i]  = base;
        base += counts[i];
    }
    if (t == 1023) offsets[N_NODES] = base;
}

// K4: dst-sorted edge records {src, bits(edge_weight)}
__global__ __launch_bounds__(256) void k_reorder(
    const int* __restrict__ ei, const float* __restrict__ ew,
    int* __restrict__ cursor, int2* __restrict__ sorted)
{
    const int e = blockIdx.x * 256 + threadIdx.x;
    if (e >= N_EDGES) return;
    const int src = ei[e];
    const int dst = ei[N_EDGES + e];
    const float w = ew[e];
    const int pos = atomicAdd(&cursor[dst], 1);
    sorted[pos] = make_int2(src, __float_as_int(w));
}

// K5: per-dst gather-aggregate, chunked online softmax.
//     Phase A: 32 lanes parallel over edges (logit+exp+reductions).
//     Phase B: 32 lanes parallel over out-cols, shfl-broadcast pe/src.
__global__ __launch_bounds__(128) void k_aggregate(
    const int2* __restrict__ sorted, const int* __restrict__ offsets,
    const float* __restrict__ attn_s4, const float* __restrict__ attn_d4,
    const __hip_bfloat16* __restrict__ h_bf, float* __restrict__ out)
{
    const int dst = blockIdx.x;
    const int tid = threadIdx.x;
    const int head = tid >> 5;
    const int lane = tid & 31;
    const int beg = offsets[dst];
    const int end = offsets[dst + 1];
    const float ad = attn_d4[dst * HEADS + head];

    float m = -1e30f, den = 0.f, acc = 0.f;
    const __hip_bfloat16* hb = h_bf + head * OUT_F + lane;

    for (int c = beg; c < end; c += 32) {
        const int cnt = min(32, end - c);
        // ---- phase A: lane = edge within chunk ----
        int sq = 0;
        float v = -1e30f;
        if (lane < cnt) {
            const int2 sw = sorted[c + lane];
            sq = sw.x;
            const float w = __int_as_float(sw.y);
            v = attn_s4[sq * HEADS + head] + ad;
            v = (v >= 0.f) ? v : NEG_SLOPE * v;
            v *= w;
        }
        float cm = v;
        #pragma unroll
        for (int s = 16; s >= 1; s >>= 1) cm = fmaxf(cm, __shfl_xor(cm, s, 32));
        const float nm = fmaxf(m, cm);
        const float scale = __expf(m - nm);        // 0 on first chunk
        const float pe = (lane < cnt) ? __expf(v - nm) : 0.f;
        float ds = pe;
        #pragma unroll
        for (int s = 16; s >= 1; s >>= 1) ds += __shfl_xor(ds, s, 32);
        den = den * scale + ds;
        m = nm;
        acc *= scale;
        // ---- phase B: lane = out col, broadcast pe/src from lane q ----
        #pragma unroll 4
        for (int q = 0; q < cnt; ++q) {
            const float peq = __shfl(pe, q, 32);
            const int   s_q = __shfl(sq, q, 32);
            acc = fmaf(peq, __bfloat162float(hb[(size_t)s_q * HO]), acc);
        }
    }
    out[dst * HO + tid] = acc / (den + 1e-10f);
}

extern "C" void kernel_launch(void* const* d_in, const int* in_sizes, int n_in,
                              void* d_out, int out_size, void* d_ws, size_t ws_size,
                              hipStream_t stream) {
    const float* x   = (const float*)d_in[0];
    const int*   ei  = (const int*)d_in[1];
    const float* ew  = (const float*)d_in[2];
    const float* W   = (const float*)d_in[3];
    const float* a_s = (const float*)d_in[4];
    const float* a_d = (const float*)d_in[5];
    float* out = (float*)d_out;

    __hip_bfloat16* h_bf = (__hip_bfloat16*)d_ws;               // N*128 bf16
    float* attn_s4 = (float*)(h_bf + (size_t)N_NODES * HO);     // N*4
    float* attn_d4 = attn_s4 + (size_t)N_NODES * HEADS;         // N*4
    int2*  sorted  = (int2*)(attn_d4 + (size_t)N_NODES * HEADS);// E int2
    int*   counts  = (int*)(sorted + N_EDGES);                  // N
    int*   offsets = counts + N_NODES;                          // N+1
    int*   cursor  = offsets + N_NODES + 1;                     // N

    hipMemsetAsync(counts, 0, N_NODES * sizeof(int), stream);

    const int histBlocks = (N_EDGES + 127) / 128;               // 12500
    k_fused1 <<<N_NODES + histBlocks, 128, 0, stream>>>(
        x, W, a_s, a_d, ei, h_bf, attn_s4, attn_d4, counts);
    k_scan   <<<1, 1024, 0, stream>>>(counts, offsets, cursor);
    k_reorder<<<(N_EDGES + 255) / 256, 256, 0, stream>>>(ei, ew, cursor, sorted);
    k_aggregate<<<N_NODES, 128, 0, stream>>>(sorted, offsets, attn_s4, attn_d4,
                                             h_bf, out);
}

// Round 4
// 538.369 us; speedup vs baseline: 2.6252x; 1.0551x over previous
//
#include <hip/hip_runtime.h>
#include <hip/hip_bf16.h>

#define N_NODES 50000
#define N_EDGES 1600000
#define IN_F 128
#define OUT_F 32
#define HEADS 4
#define NEG_SLOPE 0.2f
#define HO (HEADS * OUT_F)
#define PROJ_BLOCKS (N_NODES / 8)      // 6250, 8 nodes per block
#define REORD_BLOCKS ((N_EDGES + 255) / 256)  // 6250

// K1: in-degree histogram
__global__ __launch_bounds__(256) void k_hist(
    const int* __restrict__ ei, int* __restrict__ counts)
{
    const int e = blockIdx.x * 256 + threadIdx.x;
    if (e < N_EDGES) atomicAdd(&counts[ei[N_EDGES + e]], 1);
}

// K2: exclusive scan of counts -> offsets[N+1]; cursor initialized to offsets
__global__ __launch_bounds__(1024) void k_scan(
    const int* __restrict__ counts, int* __restrict__ offsets,
    int* __restrict__ cursor)
{
    __shared__ int part[1024];
    const int t = threadIdx.x;
    const int CH = (N_NODES + 1023) / 1024;   // 49
    const int lo = t * CH;
    const int hi = min(lo + CH, N_NODES);
    int s = 0;
    for (int i = lo; i < hi; ++i) s += counts[i];
    part[t] = s;
    __syncthreads();
    for (int d = 1; d < 1024; d <<= 1) {
        int v = (t >= d) ? part[t - d] : 0;
        __syncthreads();
        part[t] += v;
        __syncthreads();
    }
    int base = (t == 0) ? 0 : part[t - 1];
    for (int i = lo; i < hi; ++i) {
        offsets[i] = base;
        cursor[i]  = base;
        base += counts[i];
    }
    if (t == 1023) offsets[N_NODES] = base;
}

// K3 fused: even blocks reorder edges (latency/atomic-bound), odd blocks do
// the projection (VALU-bound) — co-resident so latency hides under compute.
__global__ __launch_bounds__(256) void k_fused2(
    const float* __restrict__ x, const float* __restrict__ W,
    const float* __restrict__ a_src, const float* __restrict__ a_dst,
    const int* __restrict__ ei, const float* __restrict__ ew,
    int* __restrict__ cursor, int2* __restrict__ sorted,
    __hip_bfloat16* __restrict__ h_bf, float* __restrict__ attn_s4,
    float* __restrict__ attn_d4)
{
    __shared__ float xs[8][IN_F];
    const int tid = threadIdx.x;
    if (blockIdx.x & 1) {
        // ---- reorder half: 256 edges per block ----
        const int e = (blockIdx.x >> 1) * 256 + tid;
        if (e < N_EDGES) {
            const int src = ei[e];
            const int dst = ei[N_EDGES + e];
            const float w = ew[e];
            const int pos = atomicAdd(&cursor[dst], 1);
            sorted[pos] = make_int2(src, __float_as_int(w));
        }
        return;
    }
    // ---- projection half: 8 nodes per block, 32 threads/node, 4 outs/thread
    const int pb = blockIdx.x >> 1;               // 0..6249
    ((float4*)xs)[tid] = ((const float4*)(x + (size_t)pb * 8 * IN_F))[tid];
    __syncthreads();
    const int nl = tid >> 5;                       // local node 0..7
    const int n  = pb * 8 + nl;
    const int c4 = tid & 31;                       // group of 4 outputs
    const int head = c4 >> 3;
    const int og = c4 & 7;                         // float4 index within head
    const float4* W4 = (const float4*)W;           // [H][IN_F][8]
    const float* xrow = xs[nl];
    float4 acc = {0.f, 0.f, 0.f, 0.f};
    #pragma unroll 4
    for (int k = 0; k < IN_F; ++k) {
        const float xv = xrow[k];
        const float4 w = W4[(head * IN_F + k) * 8 + og];
        acc.x = fmaf(xv, w.x, acc.x);
        acc.y = fmaf(xv, w.y, acc.y);
        acc.z = fmaf(xv, w.z, acc.z);
        acc.w = fmaf(xv, w.w, acc.w);
    }
    union { ushort4 u4; __hip_bfloat16 h[4]; } cv;
    cv.h[0] = __float2bfloat16(acc.x);
    cv.h[1] = __float2bfloat16(acc.y);
    cv.h[2] = __float2bfloat16(acc.z);
    cv.h[3] = __float2bfloat16(acc.w);
    ((ushort4*)h_bf)[(size_t)n * 32 + c4] = cv.u4;

    const float4 as4 = ((const float4*)a_src)[head * 8 + og];
    const float4 ad4 = ((const float4*)a_dst)[head * 8 + og];
    float ts = acc.x * as4.x + acc.y * as4.y + acc.z * as4.z + acc.w * as4.w;
    float td = acc.x * ad4.x + acc.y * ad4.y + acc.z * ad4.z + acc.w * ad4.w;
    #pragma unroll
    for (int s = 4; s >= 1; s >>= 1) {             // reduce over 8 og-lanes
        ts += __shfl_xor(ts, s);
        td += __shfl_xor(td, s);
    }
    if (og == 0) {
        attn_s4[n * HEADS + head] = ts;
        attn_d4[n * HEADS + head] = td;
    }
}

// K4: per-dst gather-aggregate, chunked online softmax.
__global__ __launch_bounds__(128) void k_aggregate(
    const int2* __restrict__ sorted, const int* __restrict__ offsets,
    const float* __restrict__ attn_s4, const float* __restrict__ attn_d4,
    const __hip_bfloat16* __restrict__ h_bf, float* __restrict__ out)
{
    const int dst = blockIdx.x;
    const int tid = threadIdx.x;
    const int head = tid >> 5;
    const int lane = tid & 31;
    const int beg = offsets[dst];
    const int end = offsets[dst + 1];
    const float ad = attn_d4[dst * HEADS + head];

    float m = -1e30f, den = 0.f, acc = 0.f;
    const __hip_bfloat16* hb = h_bf + head * OUT_F + lane;

    for (int c = beg; c < end; c += 32) {
        const int cnt = min(32, end - c);
        int sq = 0;
        float v = -1e30f;
        if (lane < cnt) {
            const int2 sw = sorted[c + lane];
            sq = sw.x;
            const float w = __int_as_float(sw.y);
            v = attn_s4[sq * HEADS + head] + ad;
            v = (v >= 0.f) ? v : NEG_SLOPE * v;
            v *= w;
        }
        float cm = v;
        #pragma unroll
        for (int s = 16; s >= 1; s >>= 1) cm = fmaxf(cm, __shfl_xor(cm, s, 32));
        const float nm = fmaxf(m, cm);
        const float scale = __expf(m - nm);
        const float pe = (lane < cnt) ? __expf(v - nm) : 0.f;
        float ds = pe;
        #pragma unroll
        for (int s = 16; s >= 1; s >>= 1) ds += __shfl_xor(ds, s, 32);
        den = den * scale + ds;
        m = nm;
        acc *= scale;
        #pragma unroll 4
        for (int q = 0; q < cnt; ++q) {
            const float peq = __shfl(pe, q, 32);
            const int   s_q = __shfl(sq, q, 32);
            acc = fmaf(peq, __bfloat162float(hb[(size_t)s_q * HO]), acc);
        }
    }
    out[dst * HO + tid] = acc / (den + 1e-10f);
}

extern "C" void kernel_launch(void* const* d_in, const int* in_sizes, int n_in,
                              void* d_out, int out_size, void* d_ws, size_t ws_size,
                              hipStream_t stream) {
    const float* x   = (const float*)d_in[0];
    const int*   ei  = (const int*)d_in[1];
    const float* ew  = (const float*)d_in[2];
    const float* W   = (const float*)d_in[3];
    const float* a_s = (const float*)d_in[4];
    const float* a_d = (const float*)d_in[5];
    float* out = (float*)d_out;

    __hip_bfloat16* h_bf = (__hip_bfloat16*)d_ws;               // N*128 bf16
    float* attn_s4 = (float*)(h_bf + (size_t)N_NODES * HO);     // N*4
    float* attn_d4 = attn_s4 + (size_t)N_NODES * HEADS;         // N*4
    int2*  sorted  = (int2*)(attn_d4 + (size_t)N_NODES * HEADS);// E int2
    int*   counts  = (int*)(sorted + N_EDGES);                  // N
    int*   offsets = counts + N_NODES;                          // N+1
    int*   cursor  = offsets + N_NODES + 1;                     // N

    hipMemsetAsync(counts, 0, N_NODES * sizeof(int), stream);

    k_hist <<<(N_EDGES + 255) / 256, 256, 0, stream>>>(ei, counts);
    k_scan <<<1, 1024, 0, stream>>>(counts, offsets, cursor);
    k_fused2<<<PROJ_BLOCKS + REORD_BLOCKS, 256, 0, stream>>>(
        x, W, a_s, a_d, ei, ew, cursor, sorted, h_bf, attn_s4, attn_d4);
    k_aggregate<<<N_NODES, 128, 0, stream>>>(sorted, offsets, attn_s4, attn_d4,
                                             h_bf, out);
}

// Round 5
// 446.880 us; speedup vs baseline: 3.1626x; 1.2047x over previous
//
#include <hip/hip_runtime.h>
#include <hip/hip_bf16.h>

#define N_NODES 50000
#define N_EDGES 1600000
#define IN_F 128
#define OUT_F 32
#define HEADS 4
#define NEG_SLOPE 0.2f
#define HO (HEADS * OUT_F)

#define PROJ_GRPS ((N_NODES + 31) / 32)          // 1563 groups of 32 nodes
#define PROJ_BLOCKS (PROJ_GRPS * HEADS)          // 6252
#define REORD_BLOCKS ((N_EDGES + 255) / 256)     // 6250

// K1: in-degree histogram
__global__ __launch_bounds__(256) void k_hist(
    const int* __restrict__ ei, int* __restrict__ counts)
{
    const int e = blockIdx.x * 256 + threadIdx.x;
    if (e < N_EDGES) atomicAdd(&counts[ei[N_EDGES + e]], 1);
}

// K2: exclusive scan of counts -> offsets[N+1]; cursor initialized to offsets
__global__ __launch_bounds__(1024) void k_scan(
    const int* __restrict__ counts, int* __restrict__ offsets,
    int* __restrict__ cursor)
{
    __shared__ int part[1024];
    const int t = threadIdx.x;
    const int CH = (N_NODES + 1023) / 1024;   // 49
    const int lo = t * CH;
    const int hi = min(lo + CH, N_NODES);
    int s = 0;
    for (int i = lo; i < hi; ++i) s += counts[i];
    part[t] = s;
    __syncthreads();
    for (int d = 1; d < 1024; d <<= 1) {
        int v = (t >= d) ? part[t - d] : 0;
        __syncthreads();
        part[t] += v;
        __syncthreads();
    }
    int base = (t == 0) ? 0 : part[t - 1];
    for (int i = lo; i < hi; ++i) {
        offsets[i] = base;
        cursor[i]  = base;
        base += counts[i];
    }
    if (t == 1023) offsets[N_NODES] = base;
}

// K3 fused: even blocks = projection (LDS-staged W + x, VALU-bound),
//           odd blocks  = edge reorder (atomic/scatter latency-bound).
__global__ __launch_bounds__(256) void k_fused(
    const float* __restrict__ x, const float* __restrict__ W,
    const float* __restrict__ a_src, const float* __restrict__ a_dst,
    const int* __restrict__ ei, const float* __restrict__ ew,
    int* __restrict__ cursor, int2* __restrict__ sorted,
    __hip_bfloat16* __restrict__ h_bf, float* __restrict__ attn_s4,
    float* __restrict__ attn_d4)
{
    // xs4: [32 rows][33 float4] (padded: row stride 132 words -> banks nl*4+k)
    // Ws4: [128][8] float4 (one head's W slice, 16 KB)
    __shared__ float4 lds4[32 * 33 + 1024];
    const int tid = threadIdx.x;

    if (blockIdx.x & 1) {
        // ---- reorder half: 256 edges per block ----
        const int pb = blockIdx.x >> 1;
        if (pb >= REORD_BLOCKS) return;
        const int e = pb * 256 + tid;
        if (e < N_EDGES) {
            const int src = ei[e];
            const int dst = ei[N_EDGES + e];
            const float w = ew[e];
            const int pos = atomicAdd(&cursor[dst], 1);
            sorted[pos] = make_int2(src, __float_as_int(w));
        }
        return;
    }

    // ---- projection half: 32 nodes x 1 head per block ----
    const int pb = blockIdx.x >> 1;
    if (pb >= PROJ_BLOCKS) return;
    const int head = pb & 3;
    const int grp  = pb >> 2;                 // 0..1562

    float4* xs4 = lds4;                       // [32][33]
    float4* Ws4 = lds4 + 32 * 33;             // [1024]
    const float4* W4 = (const float4*)W;      // [H][128][8]
    const float4* x4 = (const float4*)x;      // [N][32]

    #pragma unroll
    for (int t = 0; t < 4; ++t) {
        const int i = tid + t * 256;
        Ws4[i] = W4[head * 1024 + i];
        const int gi = grp * 1024 + i;
        if (gi < N_NODES * 32) xs4[(i >> 5) * 33 + (i & 31)] = x4[gi];
    }
    __syncthreads();

    const int nl = tid >> 3;                  // local node 0..31
    const int og = tid & 7;                   // float4 output group
    const int n  = grp * 32 + nl;
    if (n >= N_NODES) return;

    const float* xrow = (const float*)(xs4 + nl * 33);
    float4 acc = {0.f, 0.f, 0.f, 0.f};
    #pragma unroll 8
    for (int k = 0; k < IN_F; ++k) {
        const float xv = xrow[k];
        const float4 w = Ws4[k * 8 + og];
        acc.x = fmaf(xv, w.x, acc.x);
        acc.y = fmaf(xv, w.y, acc.y);
        acc.z = fmaf(xv, w.z, acc.z);
        acc.w = fmaf(xv, w.w, acc.w);
    }
    union { ushort4 u4; __hip_bfloat16 h[4]; } cv;
    cv.h[0] = __float2bfloat16(acc.x);
    cv.h[1] = __float2bfloat16(acc.y);
    cv.h[2] = __float2bfloat16(acc.z);
    cv.h[3] = __float2bfloat16(acc.w);
    ((ushort4*)h_bf)[(size_t)n * 32 + head * 8 + og] = cv.u4;

    const float4 as4 = ((const float4*)a_src)[head * 8 + og];
    const float4 ad4 = ((const float4*)a_dst)[head * 8 + og];
    float ts = acc.x * as4.x + acc.y * as4.y + acc.z * as4.z + acc.w * as4.w;
    float td = acc.x * ad4.x + acc.y * ad4.y + acc.z * ad4.z + acc.w * ad4.w;
    #pragma unroll
    for (int s = 4; s >= 1; s >>= 1) {
        ts += __shfl_xor(ts, s);
        td += __shfl_xor(td, s);
    }
    if (og == 0) {
        attn_s4[n * HEADS + head] = ts;
        attn_d4[n * HEADS + head] = td;
    }
}

// K4: per-dst gather-aggregate, max-first two-pass softmax (no rescale chain).
__global__ __launch_bounds__(128) void k_aggregate(
    const int2* __restrict__ sorted, const int* __restrict__ offsets,
    const float* __restrict__ attn_s4, const float* __restrict__ attn_d4,
    const __hip_bfloat16* __restrict__ h_bf, float* __restrict__ out)
{
    const int dst = blockIdx.x;
    const int tid = threadIdx.x;
    const int head = tid >> 5;
    const int lane = tid & 31;
    const int beg = offsets[dst];
    const int end = offsets[dst + 1];
    const float ad = attn_d4[dst * HEADS + head];
    const __hip_bfloat16* hb = h_bf + head * OUT_F + lane;

    // pass 1: exact per-(dst,head) max — no exp, no serialization
    float m = -1e30f;
    for (int c = beg + lane; c < end; c += 32) {
        const int2 sw = sorted[c];
        float v = attn_s4[sw.x * HEADS + head] + ad;
        v = (v >= 0.f) ? v : NEG_SLOPE * v;
        v *= __int_as_float(sw.y);
        m = fmaxf(m, v);
    }
    #pragma unroll
    for (int s = 16; s >= 1; s >>= 1) m = fmaxf(m, __shfl_xor(m, s, 32));

    // pass 2: exp + gather-accumulate, fully independent loads
    float den = 0.f, acc = 0.f;
    for (int c = beg; c < end; c += 32) {
        const int cnt = min(32, end - c);
        float pe = 0.f;
        int sq = 0;
        if (lane < cnt) {
            const int2 sw = sorted[c + lane];
            sq = sw.x;
            float v = attn_s4[sq * HEADS + head] + ad;
            v = (v >= 0.f) ? v : NEG_SLOPE * v;
            v *= __int_as_float(sw.y);
            pe = __expf(v - m);
        }
        den += pe;
        if (cnt == 32) {
            #pragma unroll
            for (int q = 0; q < 32; ++q) {
                const float peq = __shfl(pe, q, 32);
                const int   s_q = __shfl(sq, q, 32);
                acc = fmaf(peq, __bfloat162float(hb[(size_t)s_q * HO]), acc);
            }
        } else {
            for (int q = 0; q < cnt; ++q) {
                const float peq = __shfl(pe, q, 32);
                const int   s_q = __shfl(sq, q, 32);
                acc = fmaf(peq, __bfloat162float(hb[(size_t)s_q * HO]), acc);
            }
        }
    }
    #pragma unroll
    for (int s = 16; s >= 1; s >>= 1) den += __shfl_xor(den, s, 32);
    out[dst * HO + tid] = acc / (den + 1e-10f);
}

extern "C" void kernel_launch(void* const* d_in, const int* in_sizes, int n_in,
                              void* d_out, int out_size, void* d_ws, size_t ws_size,
                              hipStream_t stream) {
    const float* x   = (const float*)d_in[0];
    const int*   ei  = (const int*)d_in[1];
    const float* ew  = (const float*)d_in[2];
    const float* W   = (const float*)d_in[3];
    const float* a_s = (const float*)d_in[4];
    const float* a_d = (const float*)d_in[5];
    float* out = (float*)d_out;

    __hip_bfloat16* h_bf = (__hip_bfloat16*)d_ws;               // N*128 bf16
    float* attn_s4 = (float*)(h_bf + (size_t)N_NODES * HO);     // N*4
    float* attn_d4 = attn_s4 + (size_t)N_NODES * HEADS;         // N*4
    int2*  sorted  = (int2*)(attn_d4 + (size_t)N_NODES * HEADS);// E int2
    int*   counts  = (int*)(sorted + N_EDGES);                  // N
    int*   offsets = counts + N_NODES;                          // N+1
    int*   cursor  = offsets + N_NODES + 1;                     // N

    hipMemsetAsync(counts, 0, N_NODES * sizeof(int), stream);

    k_hist <<<(N_EDGES + 255) / 256, 256, 0, stream>>>(ei, counts);
    k_scan <<<1, 1024, 0, stream>>>(counts, offsets, cursor);
    k_fused<<<2 * PROJ_BLOCKS, 256, 0, stream>>>(
        x, W, a_s, a_d, ei, ew, cursor, sorted, h_bf, attn_s4, attn_d4);
    k_aggregate<<<N_NODES, 128, 0, stream>>>(sorted, offsets, attn_s4, attn_d4,
                                             h_bf, out);
}

// Round 6
// 377.715 us; speedup vs baseline: 3.7417x; 1.1831x over previous
//
#include <hip/hip_runtime.h>
#include <hip/hip_bf16.h>

#define N_NODES 50000
#define N_EDGES 1600000
#define IN_F 128
#define OUT_F 32
#define HEADS 4
#define NEG_SLOPE 0.2f
#define HO (HEADS * OUT_F)

#define PROJ_GRPS ((N_NODES + 31) / 32)          // 1563 groups of 32 nodes
#define PROJ_BLOCKS (PROJ_GRPS * HEADS)          // 6252
#define HIST_BLOCKS ((N_EDGES + 255) / 256)      // 6250

// K1 fused: even blocks = projection (LDS-staged W + x, VALU-bound),
//           odd blocks  = in-degree histogram, also records each edge's
//           rank within its dst segment (atomicAdd return value).
__global__ __launch_bounds__(256) void k_proj_hist(
    const float* __restrict__ x, const float* __restrict__ W,
    const float* __restrict__ a_src, const float* __restrict__ a_dst,
    const int* __restrict__ ei,
    int* __restrict__ counts, int* __restrict__ rank,
    __hip_bfloat16* __restrict__ h_bf, float* __restrict__ attn_s4,
    float* __restrict__ attn_d4)
{
    __shared__ float4 lds4[32 * 33 + 1024];   // xs[32][33] + W-slice[1024]
    const int tid = threadIdx.x;
    const int pb = blockIdx.x >> 1;

    if (blockIdx.x & 1) {
        // ---- histogram half: 256 edges per block ----
        if (pb >= HIST_BLOCKS) return;
        const int e = pb * 256 + tid;
        if (e < N_EDGES) rank[e] = atomicAdd(&counts[ei[N_EDGES + e]], 1);
        return;
    }

    // ---- projection half: 32 nodes x 1 head per block ----
    if (pb >= PROJ_BLOCKS) return;
    const int head = pb & 3;
    const int grp  = pb >> 2;                 // 0..1562

    float4* xs4 = lds4;                       // [32][33] padded
    float4* Ws4 = lds4 + 32 * 33;             // [1024]
    const float4* W4 = (const float4*)W;      // [H][128][8]
    const float4* x4 = (const float4*)x;      // [N][32]

    #pragma unroll
    for (int t = 0; t < 4; ++t) {
        const int i = tid + t * 256;
        Ws4[i] = W4[head * 1024 + i];
        const int gi = grp * 1024 + i;
        if (gi < N_NODES * 32) xs4[(i >> 5) * 33 + (i & 31)] = x4[gi];
    }
    __syncthreads();

    const int nl = tid >> 3;                  // local node 0..31
    const int og = tid & 7;                   // float4 output group
    const int n  = grp * 32 + nl;
    if (n >= N_NODES) return;

    const float* xrow = (const float*)(xs4 + nl * 33);
    float4 acc = {0.f, 0.f, 0.f, 0.f};
    #pragma unroll 8
    for (int k = 0; k < IN_F; ++k) {
        const float xv = xrow[k];
        const float4 w = Ws4[k * 8 + og];
        acc.x = fmaf(xv, w.x, acc.x);
        acc.y = fmaf(xv, w.y, acc.y);
        acc.z = fmaf(xv, w.z, acc.z);
        acc.w = fmaf(xv, w.w, acc.w);
    }
    union { ushort4 u4; __hip_bfloat16 h[4]; } cv;
    cv.h[0] = __float2bfloat16(acc.x);
    cv.h[1] = __float2bfloat16(acc.y);
    cv.h[2] = __float2bfloat16(acc.z);
    cv.h[3] = __float2bfloat16(acc.w);
    ((ushort4*)h_bf)[(size_t)n * 32 + head * 8 + og] = cv.u4;

    const float4 as4 = ((const float4*)a_src)[head * 8 + og];
    const float4 ad4 = ((const float4*)a_dst)[head * 8 + og];
    float ts = acc.x * as4.x + acc.y * as4.y + acc.z * as4.z + acc.w * as4.w;
    float td = acc.x * ad4.x + acc.y * ad4.y + acc.z * ad4.z + acc.w * ad4.w;
    #pragma unroll
    for (int s = 4; s >= 1; s >>= 1) {
        ts += __shfl_xor(ts, s);
        td += __shfl_xor(td, s);
    }
    if (og == 0) {
        attn_s4[n * HEADS + head] = ts;
        attn_d4[n * HEADS + head] = td;
    }
}

// K2: exclusive scan of counts -> offsets[N+1]
__global__ __launch_bounds__(1024) void k_scan(
    const int* __restrict__ counts, int* __restrict__ offsets)
{
    __shared__ int part[1024];
    const int t = threadIdx.x;
    const int CH = (N_NODES + 1023) / 1024;   // 49
    const int lo = t * CH;
    const int hi = min(lo + CH, N_NODES);
    int s = 0;
    for (int i = lo; i < hi; ++i) s += counts[i];
    part[t] = s;
    __syncthreads();
    for (int d = 1; d < 1024; d <<= 1) {
        int v = (t >= d) ? part[t - d] : 0;
        __syncthreads();
        part[t] += v;
        __syncthreads();
    }
    int base = (t == 0) ? 0 : part[t - 1];
    for (int i = lo; i < hi; ++i) {
        offsets[i] = base;
        base += counts[i];
    }
    if (t == 1023) offsets[N_NODES] = base;
}

// K3: atomic-free scatter with per-edge logit precompute.
//     pos = offsets[dst] + rank[e]; write srcs[pos], logits4[pos].
__global__ __launch_bounds__(256) void k_edges(
    const int* __restrict__ ei, const float* __restrict__ ew,
    const int* __restrict__ rank, const int* __restrict__ offsets,
    const float* __restrict__ attn_s4, const float* __restrict__ attn_d4,
    int* __restrict__ srcs, float4* __restrict__ logits4)
{
    const int e = blockIdx.x * 256 + threadIdx.x;
    if (e >= N_EDGES) return;
    const int src = ei[e];
    const int dst = ei[N_EDGES + e];
    const float w = ew[e];
    const int pos = offsets[dst] + rank[e];
    const float4 as = ((const float4*)attn_s4)[src];
    const float4 ad = ((const float4*)attn_d4)[dst];
    float4 l;
    l.x = as.x + ad.x; l.x = ((l.x >= 0.f) ? l.x : NEG_SLOPE * l.x) * w;
    l.y = as.y + ad.y; l.y = ((l.y >= 0.f) ? l.y : NEG_SLOPE * l.y) * w;
    l.z = as.z + ad.z; l.z = ((l.z >= 0.f) ? l.z : NEG_SLOPE * l.z) * w;
    l.w = as.w + ad.w; l.w = ((l.w >= 0.f) ? l.w : NEG_SLOPE * l.w) * w;
    srcs[pos] = src;
    logits4[pos] = l;
}

// K4: per-dst gather-aggregate; max-first two-pass over coalesced logit
//     records, then broadcast-FMA over gathered bf16 h rows.
__global__ __launch_bounds__(128) void k_aggregate(
    const int* __restrict__ srcs, const float4* __restrict__ logits4,
    const int* __restrict__ offsets, const __hip_bfloat16* __restrict__ h_bf,
    float* __restrict__ out)
{
    const int dst = blockIdx.x;
    const int tid = threadIdx.x;
    const int head = tid >> 5;
    const int lane = tid & 31;
    const int beg = offsets[dst];
    const int end = offsets[dst + 1];
    const float* lg = (const float*)logits4 + head;   // scalar view, stride 4
    const __hip_bfloat16* hb = h_bf + head * OUT_F + lane;

    // pass 1: per-(dst,head) max over coalesced logit records
    float m = -1e30f;
    for (int c = beg + lane; c < end; c += 32)
        m = fmaxf(m, lg[(size_t)c * 4]);
    #pragma unroll
    for (int s = 16; s >= 1; s >>= 1) m = fmaxf(m, __shfl_xor(m, s, 32));

    // pass 2: exp + gather-accumulate (2 independent acc chains)
    float den = 0.f, acc0 = 0.f, acc1 = 0.f;
    for (int c = beg; c < end; c += 32) {
        const int cnt = min(32, end - c);
        float pe = 0.f;
        int sq = 0;
        if (lane < cnt) {
            sq = srcs[c + lane];
            pe = __expf(lg[(size_t)(c + lane) * 4] - m);
        }
        den += pe;
        if (cnt == 32) {
            #pragma unroll
            for (int q = 0; q < 32; q += 2) {
                const float p0 = __shfl(pe, q, 32);
                const int   s0 = __shfl(sq, q, 32);
                const float p1 = __shfl(pe, q + 1, 32);
                const int   s1 = __shfl(sq, q + 1, 32);
                acc0 = fmaf(p0, __bfloat162float(hb[(size_t)s0 * HO]), acc0);
                acc1 = fmaf(p1, __bfloat162float(hb[(size_t)s1 * HO]), acc1);
            }
        } else {
            for (int q = 0; q < cnt; ++q) {
                const float p0 = __shfl(pe, q, 32);
                const int   s0 = __shfl(sq, q, 32);
                acc0 = fmaf(p0, __bfloat162float(hb[(size_t)s0 * HO]), acc0);
            }
        }
    }
    #pragma unroll
    for (int s = 16; s >= 1; s >>= 1) den += __shfl_xor(den, s, 32);
    out[dst * HO + tid] = (acc0 + acc1) / (den + 1e-10f);
}

extern "C" void kernel_launch(void* const* d_in, const int* in_sizes, int n_in,
                              void* d_out, int out_size, void* d_ws, size_t ws_size,
                              hipStream_t stream) {
    const float* x   = (const float*)d_in[0];
    const int*   ei  = (const int*)d_in[1];
    const float* ew  = (const float*)d_in[2];
    const float* W   = (const float*)d_in[3];
    const float* a_s = (const float*)d_in[4];
    const float* a_d = (const float*)d_in[5];
    float* out = (float*)d_out;

    __hip_bfloat16* h_bf = (__hip_bfloat16*)d_ws;                 // 12.8 MB
    float*  attn_s4 = (float*)(h_bf + (size_t)N_NODES * HO);      // 800 KB
    float*  attn_d4 = attn_s4 + (size_t)N_NODES * HEADS;          // 800 KB
    float4* logits4 = (float4*)(attn_d4 + (size_t)N_NODES * HEADS); // 25.6 MB (16B-aligned)
    int*    srcs    = (int*)(logits4 + N_EDGES);                  // 6.4 MB
    int*    rank    = srcs + N_EDGES;                             // 6.4 MB
    int*    counts  = rank + N_EDGES;                             // 200 KB
    int*    offsets = counts + N_NODES;                           // 200 KB

    hipMemsetAsync(counts, 0, N_NODES * sizeof(int), stream);

    k_proj_hist<<<2 * PROJ_BLOCKS, 256, 0, stream>>>(
        x, W, a_s, a_d, ei, counts, rank, h_bf, attn_s4, attn_d4);
    k_scan<<<1, 1024, 0, stream>>>(counts, offsets);
    k_edges<<<(N_EDGES + 255) / 256, 256, 0, stream>>>(
        ei, ew, rank, offsets, attn_s4, attn_d4, srcs, logits4);
    k_aggregate<<<N_NODES, 128, 0, stream>>>(srcs, logits4, offsets, h_bf, out);
}